// Round 3
// baseline (348.919 us; speedup 1.0000x reference)
//
#include <hip/hip_runtime.h>
#include <stdint.h>

// Problem constants (AdaBIGGAN last adaptive-conv stage), all tensors float32.
#define B_  32
#define C_  96
#define HW_ 16384   // 128*128
#define IN_ 148

typedef float f32x4 __attribute__((ext_vector_type(4)));

// ---------------------------------------------------------------------------
// Kernel 1: hypernetwork collapse.
//   scale[b,c] = y[b,:] . Wsum[c,:] + WbSum[c]
//   bias [b,c] = y[b,:] . Bg_w[c,:] + Bg_b[c]
// where Wsum[c,i] = sum_j Wg_w[(c*96+j)*148 + i], WbSum[c] = sum_j Wg_b[c*96+j].
// One block per c (96 blocks, 512 threads = 8 waves). Column sums split 2-way
// across rows to halve the dependent-load chain.
// ---------------------------------------------------------------------------
__global__ __launch_bounds__(512) void hyper_kernel(
    const float* __restrict__ Wg_w, const float* __restrict__ Wg_b,
    const float* __restrict__ Bg_w, const float* __restrict__ Bg_b,
    const float* __restrict__ y,
    float* __restrict__ scale, float* __restrict__ bias) {
    const int c   = blockIdx.x;
    const int tid = threadIdx.x;

    __shared__ float sW2[2][IN_];  // partial column sums (rows 0..47 / 48..95)
    __shared__ float sW[IN_];      // combined column sums
    __shared__ float sB[IN_];      // Bg_w row for this c
    __shared__ float sWbS;         // sum of the Wg_b chunk

    if (tid < 2 * IN_) {
        const int half = (tid >= IN_) ? 1 : 0;
        const int col  = tid - half * IN_;
        const float* p = Wg_w + (size_t)c * C_ * IN_ + (size_t)(half * 48) * IN_ + col;
        float s = 0.f;
        #pragma unroll 4
        for (int j = 0; j < 48; ++j) s += p[(size_t)j * IN_];
        sW2[half][col] = s;
        if (half == 0) sB[col] = Bg_w[c * IN_ + col];
    }
    if (tid < 64) {  // sum of 96 Wg_b entries, wave 0
        float v = Wg_b[c * C_ + tid];
        if (tid < C_ - 64) v += Wg_b[c * C_ + 64 + tid];
        #pragma unroll
        for (int off = 32; off > 0; off >>= 1) v += __shfl_down(v, off);
        if (tid == 0) sWbS = v;
    }
    __syncthreads();
    if (tid < IN_) sW[tid] = sW2[0][tid] + sW2[1][tid];
    __syncthreads();

    const int wave = tid >> 6, lane = tid & 63;
    for (int b = wave; b < B_; b += 8) {
        float y0 = y[b * IN_ + lane];
        float y1 = y[b * IN_ + 64 + lane];
        float ps = y0 * sW[lane] + y1 * sW[64 + lane];
        float pb = y0 * sB[lane] + y1 * sB[64 + lane];
        if (lane < IN_ - 128) {   // 148 = 64 + 64 + 20
            float y2 = y[b * IN_ + 128 + lane];
            ps += y2 * sW[128 + lane];
            pb += y2 * sB[128 + lane];
        }
        #pragma unroll
        for (int off = 32; off > 0; off >>= 1) {
            ps += __shfl_down(ps, off);
            pb += __shfl_down(pb, off);
        }
        if (lane == 0) {
            scale[b * C_ + c] = ps + sWbS;
            bias [b * C_ + c] = pb + Bg_b[c];
        }
    }
}

// ---------------------------------------------------------------------------
// Kernel 2: out = relu(h * scale[plane] + bias[plane]).
// Each thread handles two consecutive float4s (32 B). 2048 chunks per plane,
// 256 threads/block -> plane uniform per block.
// ---------------------------------------------------------------------------
__global__ __launch_bounds__(256) void apply_kernel(
    const float* __restrict__ h, const float* __restrict__ scale,
    const float* __restrict__ bias, float* __restrict__ out) {
    const int cidx  = blockIdx.x * 256 + threadIdx.x;  // 32B-chunk index
    const int plane = cidx >> 11;                       // / (HW/8)

    const float s  = scale[plane];
    const float bb = bias[plane];

    const f32x4* hp = reinterpret_cast<const f32x4*>(h) + (size_t)cidx * 2;
    f32x4*       op = reinterpret_cast<f32x4*>(out)     + (size_t)cidx * 2;

    f32x4 v0 = __builtin_nontemporal_load(hp);
    f32x4 v1 = __builtin_nontemporal_load(hp + 1);
    f32x4 o0, o1;
    #pragma unroll
    for (int k = 0; k < 4; ++k) {
        o0[k] = fmaxf(fmaf(v0[k], s, bb), 0.f);
        o1[k] = fmaxf(fmaf(v1[k], s, bb), 0.f);
    }
    __builtin_nontemporal_store(o0, op);
    __builtin_nontemporal_store(o1, op + 1);
}

extern "C" void kernel_launch(void* const* d_in, const int* in_sizes, int n_in,
                              void* d_out, int out_size, void* d_ws, size_t ws_size,
                              hipStream_t stream) {
    const float* h    = (const float*)d_in[0];
    const float* y    = (const float*)d_in[1];
    const float* Wg_w = (const float*)d_in[2];
    const float* Wg_b = (const float*)d_in[3];
    const float* Bg_w = (const float*)d_in[4];
    const float* Bg_b = (const float*)d_in[5];
    float* out = (float*)d_out;

    // f32 scratch in d_ws: scale[B*C] then bias[B*C] (24 KB total).
    float* scale = (float*)d_ws;
    float* bias  = scale + B_ * C_;

    hyper_kernel<<<C_, 512, 0, stream>>>(Wg_w, Wg_b, Bg_w, Bg_b, y, scale, bias);

    const int nchunk = (B_ * C_ * HW_) / 8;            // 6,291,456 32B chunks
    apply_kernel<<<nchunk / 256, 256, 0, stream>>>(h, scale, bias, out);
}